// Round 2
// baseline (239.092 us; speedup 1.0000x reference)
//
#include <hip/hip_runtime.h>
#include <hip/hip_bf16.h>

#define NA 8400
#define BS 64
#define NC 80
#define TOPK 13
#define EPSF 1e-9f

// ---------------------------------------------------------------------------
// Kernel A: one block per batch. Computes align metric, top-13, mask_pos row,
// and scatters v = align*pos_ov/(pos_align+EPS) into norm[] via atomicMax.
// ---------------------------------------------------------------------------
__global__ __launch_bounds__(256) void assign_kernel(
    const float* __restrict__ pd_scores,   // (BS, NC, NA)
    const float* __restrict__ pd_bboxes,   // (BS, 4, NA)
    const int*   __restrict__ gt_labels,   // (BS,)
    const float* __restrict__ gt_bboxes,   // (BS, 4)
    float*       __restrict__ out_mask,    // (BS, NA)  = d_out + NA*BS
    float*       __restrict__ norm)        // (NA,) f32 ws, pre-zeroed
{
    __shared__ float s_align[NA];
    __shared__ float s_redv[4];
    __shared__ int   s_redi[4];
    __shared__ int   s_sel[TOPK];
    __shared__ float s_selv[TOPK];
    __shared__ float s_selov[TOPK];
    __shared__ float s_mask;

    const int b = blockIdx.x;
    const int t = threadIdx.x;
    const int wave = t >> 6, lane = t & 63;

    // gt box (broadcast to all threads)
    const float p1x = gt_bboxes[b * 4 + 0];
    const float p1y = gt_bboxes[b * 4 + 1];
    const float p2x = gt_bboxes[b * 4 + 2];
    const float p2y = gt_bboxes[b * 4 + 3];
    const float area1 = fmaxf(p2x - p1x, 0.f) * fmaxf(p2y - p1y, 0.f);
    const int lbl = gt_labels[b];
    const float* sc = pd_scores + (size_t)b * NC * NA + (size_t)lbl * NA;
    const float* bb = pd_bboxes + (size_t)b * 4 * NA;

    // align metric into LDS
    for (int a = t; a < NA; a += 256) {
        float g1x = bb[0 * NA + a];
        float g1y = bb[1 * NA + a];
        float g2x = bb[2 * NA + a];
        float g2y = bb[3 * NA + a];
        float wx = fmaxf(fminf(p2x, g2x) - fmaxf(p1x, g1x), 0.f);
        float wy = fmaxf(fminf(p2y, g2y) - fmaxf(p1y, g1y), 0.f);
        float ovl = wx * wy;
        float area2 = fmaxf(g2x - g1x, 0.f) * fmaxf(g2y - g1y, 0.f);
        float o = ovl / (area1 + area2 - ovl + EPSF);
        float o2 = o * o;
        float score = sc[a];
        s_align[a] = score * (o2 * o2 * o2);   // score^1 * o^6
    }
    __syncthreads();

    // 13 iterative block argmax passes (tie -> smallest index, matches top_k)
    for (int j = 0; j < TOPK; ++j) {
        float bv = -2.f;
        int   bi = 0x7fffffff;
        for (int a = t; a < NA; a += 256) {
            float v = s_align[a];
            if (v > bv) { bv = v; bi = a; }   // strict > keeps smallest index
        }
        #pragma unroll
        for (int off = 32; off > 0; off >>= 1) {
            float ov_ = __shfl_down(bv, off);
            int   oi_ = __shfl_down(bi, off);
            if (ov_ > bv || (ov_ == bv && oi_ < bi)) { bv = ov_; bi = oi_; }
        }
        if (lane == 0) { s_redv[wave] = bv; s_redi[wave] = bi; }
        __syncthreads();
        if (t == 0) {
            for (int w = 1; w < 4; ++w) {
                float ov_ = s_redv[w]; int oi_ = s_redi[w];
                if (ov_ > bv || (ov_ == bv && oi_ < bi)) { bv = ov_; bi = oi_; }
            }
            s_sel[j] = bi; s_selv[j] = bv;
            s_align[bi] = -1.0f;   // exclude (align >= 0, so -1 is unambiguous)
        }
        __syncthreads();
    }

    // recompute overlaps for the 13 winners (exact same f32 op sequence)
    if (t < TOPK) {
        int a = s_sel[t];
        float g1x = bb[0 * NA + a];
        float g1y = bb[1 * NA + a];
        float g2x = bb[2 * NA + a];
        float g2y = bb[3 * NA + a];
        float wx = fmaxf(fminf(p2x, g2x) - fmaxf(p1x, g1x), 0.f);
        float wy = fmaxf(fminf(p2y, g2y) - fmaxf(p1y, g1y), 0.f);
        float ovl = wx * wy;
        float area2 = fmaxf(g2x - g1x, 0.f) * fmaxf(g2y - g1y, 0.f);
        s_selov[t] = ovl / (area1 + area2 - ovl + EPSF);
    }
    __syncthreads();

    if (t == 0) {
        float pos_align = s_selv[0];               // top-1 = row max
        bool mask = pos_align > EPSF;
        s_mask = mask ? 1.f : 0.f;
        if (mask) {
            float pos_ov = 0.f;
            for (int j = 0; j < TOPK; ++j) pos_ov = fmaxf(pos_ov, s_selov[j]);
            for (int j = 0; j < TOPK; ++j) {
                float v = (s_selv[j] * pos_ov) / (pos_align + EPSF);
                atomicMax((int*)&norm[s_sel[j]], __float_as_int(v)); // v >= 0
            }
        }
    }
    __syncthreads();

    // write mask_pos row (selected entries were overwritten with -1.0f)
    const float maskf = s_mask;
    for (int a = t; a < NA; a += 256) {
        bool sel = (s_align[a] == -1.0f) && (maskf > 0.5f);
        out_mask[(size_t)b * NA + a] = sel ? 1.0f : 0.0f;
    }
}

// ---------------------------------------------------------------------------
// Kernel B: out0[a*64 + b] = float(gt_labels[b]) * norm[a]   (shape (NA, BS))
// ---------------------------------------------------------------------------
__global__ __launch_bounds__(256) void scores_kernel(
    const float* __restrict__ norm,
    const int*   __restrict__ gt_labels,
    float*       __restrict__ out0)
{
    int idx = blockIdx.x * 256 + threadIdx.x;
    if (idx >= NA * BS) return;
    int b = idx & (BS - 1);
    int a = idx >> 6;
    float v = (float)gt_labels[b] * norm[a];
    out0[idx] = v;
}

extern "C" void kernel_launch(void* const* d_in, const int* in_sizes, int n_in,
                              void* d_out, int out_size, void* d_ws, size_t ws_size,
                              hipStream_t stream) {
    const float* pd_scores = (const float*)d_in[0];
    const float* pd_bboxes = (const float*)d_in[1];
    const int*   gt_labels = (const int*)d_in[2];
    const float* gt_bboxes = (const float*)d_in[3];

    float* out0     = (float*)d_out;                  // (NA, BS)
    float* out_mask = out0 + (size_t)NA * BS;         // (BS, NA)
    float* norm     = (float*)d_ws;                   // (NA,)

    hipMemsetAsync(norm, 0, NA * sizeof(float), stream);
    assign_kernel<<<BS, 256, 0, stream>>>(pd_scores, pd_bboxes, gt_labels,
                                          gt_bboxes, out_mask, norm);
    scores_kernel<<<(NA * BS + 255) / 256, 256, 0, stream>>>(norm, gt_labels, out0);
}